// Round 2
// baseline (245.117 us; speedup 1.0000x reference)
//
#include <hip/hip_runtime.h>
#include <math.h>

#define BB 2
#define NN 512
#define DD 128
#define HH 8
#define DKK 16

// ---------------- Kernel 1: QKV projection ----------------
// qkv = n @ W_qkv ; store Q,K,V as [B,H,N,DK]
__global__ __launch_bounds__(128)
void qkv_kernel(const float* __restrict__ n_in,
                const float* __restrict__ W_qkv,
                float* __restrict__ Qw, float* __restrict__ Kw, float* __restrict__ Vw)
{
    __shared__ float nrow[DD];
    const int bn = blockIdx.x;           // b*N + n
    const int b  = bn >> 9;
    const int nr = bn & 511;
    const int t  = threadIdx.x;          // 0..127
    nrow[t] = n_in[(size_t)bn * DD + t];
    __syncthreads();
    const int h = t >> 4, dk = t & 15;
    const size_t dst = ((size_t)(b * HH + h) * NN + nr) * DKK + dk;
    float accq = 0.f, acck = 0.f, accv = 0.f;
    #pragma unroll 8
    for (int d = 0; d < DD; ++d) {
        const float nv = nrow[d];
        const float* wr = W_qkv + (size_t)d * 3 * DD;
        accq += nv * wr[t];
        acck += nv * wr[t + 128];
        accv += nv * wr[t + 256];
    }
    Qw[dst] = accq;
    Kw[dst] = acck;
    Vw[dst] = accv;
}

// ---------------- Kernel 2: fused edge-bias attention ----------------
// One block per (b,n). 256 threads = 4 waves.
__global__ __launch_bounds__(256)
void fused_kernel(const float* __restrict__ e,
                  const float* __restrict__ W_g,
                  const float* __restrict__ W_e,
                  const float* __restrict__ O_n,
                  const float* __restrict__ O_e,
                  const float* __restrict__ Qw,
                  const float* __restrict__ Kw,
                  const float* __restrict__ Vw,
                  float* __restrict__ n_out,
                  float* __restrict__ e_out)
{
    __shared__ __align__(16) float E_lds[HH * NN];     // scores [h][m] (E, then _E)
    __shared__ __align__(16) float W_egT[16 * DD];     // [hh][d]; hh<8: W_e col, hh>=8: W_g col
    __shared__ __align__(16) float Oe_lds[HH * DD];    // [h][d]
    __shared__ __align__(16) float q_lds[DD];          // Q row, h-major
    __shared__ __align__(16) float vout[DD];           // _V * dyn_cent, h-major
    __shared__ float gsum_raw[HH];
    __shared__ float dc[HH];

    const int t    = threadIdx.x;
    const int bn   = blockIdx.x;
    const int b    = bn >> 9;
    const int nr   = bn & 511;
    const int wq   = t >> 6;     // wave 0..3
    const int lane = t & 63;

    // ---- stage small matrices (transposed W_e|W_g so columns are contiguous) ----
    for (int i = t; i < 16 * DD; i += 256) {
        const int hh = i >> 7, d = i & 127;
        W_egT[i] = (hh < 8) ? W_e[d * HH + hh] : W_g[d * HH + (hh - 8)];
    }
    for (int i = t; i < HH * DD; i += 256) Oe_lds[i] = O_e[i];
    if (t < DD) {
        q_lds[t] = Qw[((size_t)(b * HH + (t >> 4)) * NN + nr) * DKK + (t & 15)];
    }
    __syncthreads();

    // ---- Phase A: E[h][m] (waves 0,1) and G row-sums (waves 2,3) ----
    // wave wq owns columns hh = 4*wq .. 4*wq+3; lanes sweep all 512 rows.
    float acc[4][8];
    #pragma unroll
    for (int j = 0; j < 4; ++j)
        #pragma unroll
        for (int s = 0; s < 8; ++s) acc[j][s] = 0.f;

    const float4* __restrict__ e4 = (const float4*)(e + (size_t)bn * NN * DD);
    for (int d16 = 0; d16 < 8; ++d16) {
        float4 w4[4][4];   // 4 hh-columns x 16 d values, wave-uniform broadcast loads
        #pragma unroll
        for (int j = 0; j < 4; ++j) {
            #pragma unroll
            for (int k = 0; k < 4; ++k)
                w4[j][k] = *(const float4*)&W_egT[(4 * wq + j) * DD + d16 * 16 + k * 4];
        }
        #pragma unroll
        for (int s = 0; s < 8; ++s) {
            const float4* ep = e4 + (size_t)(s * 64 + lane) * 32 + d16 * 4; // 64B/lane
            #pragma unroll
            for (int k = 0; k < 4; ++k) {
                const float4 ev = ep[k];
                #pragma unroll
                for (int j = 0; j < 4; ++j)
                    acc[j][s] += ev.x * w4[j][k].x + ev.y * w4[j][k].y
                               + ev.z * w4[j][k].z + ev.w * w4[j][k].w;
            }
        }
    }

    if (wq < 2) {
        #pragma unroll
        for (int j = 0; j < 4; ++j) {
            const int h = 4 * wq + j;
            #pragma unroll
            for (int s = 0; s < 8; ++s)
                E_lds[h * NN + s * 64 + lane] = acc[j][s];
        }
    } else {
        #pragma unroll
        for (int j = 0; j < 4; ++j) {
            float gs = 0.f;
            #pragma unroll
            for (int s = 0; s < 8; ++s)
                gs += 1.f / (1.f + __expf(-acc[j][s]));
            #pragma unroll
            for (int off = 32; off >= 1; off >>= 1)
                gs += __shfl_xor(gs, off, 64);
            if (lane == 0) gsum_raw[(wq - 2) * 4 + j] = gs;
        }
    }
    __syncthreads();
    if (t < HH) dc[t] = log1pf(gsum_raw[t]);
    __syncthreads();

    // ---- Phase B: scores + softmax + AV. Each wave handles 2 heads. ----
    #pragma unroll 1
    for (int hw = 0; hw < 2; ++hw) {
        const int h = wq * 2 + hw;
        const float4* __restrict__ kb =
            (const float4*)(Kw + ((size_t)(b * HH + h) * NN) * DKK);
        const float4 q0 = *(const float4*)&q_lds[h * 16 + 0];
        const float4 q1 = *(const float4*)&q_lds[h * 16 + 4];
        const float4 q2 = *(const float4*)&q_lds[h * 16 + 8];
        const float4 q3 = *(const float4*)&q_lds[h * 16 + 12];
        float vals[8];
        float rmax = -1e30f;
        #pragma unroll
        for (int k = 0; k < 8; ++k) {
            const int m = k * 64 + lane;
            const float4 k0 = kb[m * 4 + 0];
            const float4 k1 = kb[m * 4 + 1];
            const float4 k2 = kb[m * 4 + 2];
            const float4 k3 = kb[m * 4 + 3];
            float s = q0.x*k0.x + q0.y*k0.y + q0.z*k0.z + q0.w*k0.w
                    + q1.x*k1.x + q1.y*k1.y + q1.z*k1.z + q1.w*k1.w
                    + q2.x*k2.x + q2.y*k2.y + q2.z*k2.z + q2.w*k2.w
                    + q3.x*k3.x + q3.y*k3.y + q3.z*k3.z + q3.w*k3.w;
            s *= 0.25f;                       // DK^-0.5
            s = fminf(5.f, fmaxf(-5.f, s));   // clamp BEFORE adding E
            const float val = s + E_lds[h * NN + m];
            E_lds[h * NN + m] = val;          // _E, kept for e_out
            vals[k] = val;
            rmax = fmaxf(rmax, val);
        }
        #pragma unroll
        for (int off = 32; off >= 1; off >>= 1)
            rmax = fmaxf(rmax, __shfl_xor(rmax, off, 64));
        float sum = 0.f;
        #pragma unroll
        for (int k = 0; k < 8; ++k) sum += __expf(vals[k] - rmax);
        #pragma unroll
        for (int off = 32; off >= 1; off >>= 1)
            sum += __shfl_xor(sum, off, 64);
        const float factor = dc[h] / sum;     // softmax denom + dyn_cent scale
        __syncthreads();                      // make _E writes lane-visible
        // AV: lanes = 16 d x 4 m-groups
        const int ddx = lane & 15, mg = lane >> 4;
        const float* __restrict__ vb = Vw + ((size_t)(b * HH + h) * NN) * DKK;
        float av = 0.f;
        #pragma unroll 4
        for (int m = mg; m < NN; m += 4) {
            const float p = __expf(E_lds[h * NN + m] - rmax);
            av += p * vb[m * DKK + ddx];
        }
        av += __shfl_xor(av, 16, 64);
        av += __shfl_xor(av, 32, 64);
        if (mg == 0) vout[h * DKK + ddx] = av * factor;
    }
    __syncthreads();

    // ---- Phase C: n_out = vout @ O_n ----
    if (t < DD) {
        float a3 = 0.f;
        #pragma unroll 4
        for (int d = 0; d < DD; ++d) a3 += vout[d] * O_n[d * DD + t];
        n_out[(size_t)bn * DD + t] = a3;
    }

    // ---- Phase D: e_out[m,:] = sum_h _E[h][m] * O_e[h,:] ----
    const int c4 = t & 31;     // float4 column (fixed per thread)
    const int m0 = t >> 5;     // 0..7
    float4 oe[8];
    #pragma unroll
    for (int h = 0; h < 8; ++h)
        oe[h] = *(const float4*)&Oe_lds[h * DD + c4 * 4];
    float4* __restrict__ out4 = (float4*)(e_out + (size_t)bn * NN * DD);
    for (int k = 0; k < 64; ++k) {
        const int m = m0 + k * 8;
        float4 r{0.f, 0.f, 0.f, 0.f};
        #pragma unroll
        for (int h = 0; h < 8; ++h) {
            const float ev = E_lds[h * NN + m];   // broadcast read
            r.x += ev * oe[h].x;
            r.y += ev * oe[h].y;
            r.z += ev * oe[h].z;
            r.w += ev * oe[h].w;
        }
        out4[(size_t)m * 32 + c4] = r;
    }
}

extern "C" void kernel_launch(void* const* d_in, const int* in_sizes, int n_in,
                              void* d_out, int out_size, void* d_ws, size_t ws_size,
                              hipStream_t stream)
{
    const float* n_ptr = (const float*)d_in[0];
    const float* e     = (const float*)d_in[1];
    const float* W_qkv = (const float*)d_in[2];
    const float* O_n   = (const float*)d_in[3];
    const float* W_g   = (const float*)d_in[4];
    const float* W_e   = (const float*)d_in[5];
    const float* O_e   = (const float*)d_in[6];

    float* n_out = (float*)d_out;
    float* e_out = n_out + (size_t)BB * NN * DD;       // outputs concat flat

    float* Qw = (float*)d_ws;                           // [B,H,N,DK] each
    float* Kw = Qw + (size_t)BB * HH * NN * DKK;
    float* Vw = Kw + (size_t)BB * HH * NN * DKK;

    qkv_kernel<<<BB * NN, 128, 0, stream>>>(n_ptr, W_qkv, Qw, Kw, Vw);
    fused_kernel<<<BB * NN, 256, 0, stream>>>(e, W_g, W_e, O_n, O_e,
                                              Qw, Kw, Vw, n_out, e_out);
}